// Round 1
// baseline (1032.658 us; speedup 1.0000x reference)
//
#include <hip/hip_runtime.h>

// Problem: B=256, C=2048, N=H*W=288, K=6, fp32.
// out[b,c,k] = mean over {n: argmin_k dist(x[b,:,n], cluster_k)} of x[b,c,n], 0 if empty.
// Memory-bound: x streamed twice (dots need full-C reduction before assignment is known).

#define NB 256
#define NC 2048
#define NN 288
#define NK 6
#define NT 1024
#define NJ 72   // n-groups of 4 (72*4 = 288)
#define NP 14   // c-parallel slices; 72*14 = 1008 active threads in phase 1

__global__ __launch_bounds__(NT) void cluster_kernel(
    const float* __restrict__ x,
    const float* __restrict__ cl,
    float* __restrict__ out)
{
    // fp64 partial dots folded 14 -> 4 slices: 4*288*6*8 = 55,296 B
    __shared__ double part[4][NN][NK];
    __shared__ double cn_part[NP][NK];
    __shared__ double cnorm_s[NK];
    __shared__ unsigned assign_u[NN / 4];   // assignment bytes, 4 n per word
    __shared__ int counts[NK];
    __shared__ float inv_s[NK];

    const int tid = threadIdx.x;
    const int b = blockIdx.x;
    const float* xb = x + (size_t)b * (size_t)(NC * NN);

    if (tid < NK) counts[tid] = 0;

    const int j = tid % NJ;     // n-group: n = 4j..4j+3
    const int p = tid / NJ;     // c-slice: c = p, p+14, ...

    // ---------------- Phase 1: dot[n][k] = sum_c x[b,c,n] * cl[k][c] ----------------
    double acc[4][NK];
    double cn[NK];
#pragma unroll
    for (int r = 0; r < 4; ++r)
#pragma unroll
        for (int k = 0; k < NK; ++k) acc[r][k] = 0.0;
#pragma unroll
    for (int k = 0; k < NK; ++k) cn[k] = 0.0;

    if (p < NP) {
#pragma unroll 2
        for (int c = p; c < NC; c += NP) {
            float4 v = *(const float4*)(xb + (size_t)c * NN + 4 * j);
            double vx = v.x, vy = v.y, vz = v.z, vw = v.w;
#pragma unroll
            for (int k = 0; k < NK; ++k) {
                double ck = (double)cl[k * NC + c];
                cn[k] += ck * ck;
                acc[0][k] += vx * ck;
                acc[1][k] += vy * ck;
                acc[2][k] += vz * ck;
                acc[3][k] += vw * ck;
            }
        }
    }

    // fold 14 c-slices into 4 LDS partials: part[q] accumulates p in {q, q+4, q+8, q+12}
    if (p < 4) {
#pragma unroll
        for (int r = 0; r < 4; ++r)
#pragma unroll
            for (int k = 0; k < NK; ++k) part[p][4 * j + r][k] = acc[r][k];
        if (j == 0) {
#pragma unroll
            for (int k = 0; k < NK; ++k) cn_part[p][k] = cn[k];
        }
    }
    __syncthreads();
    if (p >= 4 && p < 8) {
#pragma unroll
        for (int r = 0; r < 4; ++r)
#pragma unroll
            for (int k = 0; k < NK; ++k) part[p - 4][4 * j + r][k] += acc[r][k];
        if (j == 0) {
#pragma unroll
            for (int k = 0; k < NK; ++k) cn_part[p][k] = cn[k];
        }
    }
    __syncthreads();
    if (p >= 8 && p < 12) {
#pragma unroll
        for (int r = 0; r < 4; ++r)
#pragma unroll
            for (int k = 0; k < NK; ++k) part[p - 8][4 * j + r][k] += acc[r][k];
        if (j == 0) {
#pragma unroll
            for (int k = 0; k < NK; ++k) cn_part[p][k] = cn[k];
        }
    }
    __syncthreads();
    if (p >= 12 && p < NP) {
#pragma unroll
        for (int r = 0; r < 4; ++r)
#pragma unroll
            for (int k = 0; k < NK; ++k) part[p - 12][4 * j + r][k] += acc[r][k];
        if (j == 0) {
#pragma unroll
            for (int k = 0; k < NK; ++k) cn_part[p][k] = cn[k];
        }
    }
    __syncthreads();

    if (tid < NK) {
        double s = 0.0;
        for (int q = 0; q < NP; ++q) s += cn_part[q][tid];
        cnorm_s[tid] = s;
    }
    __syncthreads();

    // argmin_k (||c_k||^2 - 2 dot) — x_norm is common across k, drop it.
    // Strict < with ascending k == numpy first-min tie-breaking.
    if (tid < NN) {
        double best = 1e300;
        int bi = 0;
#pragma unroll
        for (int k = 0; k < NK; ++k) {
            double d = 0.0;
#pragma unroll
            for (int q = 0; q < 4; ++q) d += part[q][tid][k];
            double sc = cnorm_s[k] - 2.0 * d;
            if (sc < best) { best = sc; bi = k; }
        }
        ((unsigned char*)assign_u)[tid] = (unsigned char)bi;
        atomicAdd(&counts[bi], 1);
    }
    __syncthreads();
    if (tid < NK) inv_s[tid] = counts[tid] > 0 ? 1.0f / (float)counts[tid] : 0.0f;
    __syncthreads();

    // ---------------- Phase 2: per-c masked sums over n, wave <-> c ----------------
    const int w = tid >> 6;
    const int lane = tid & 63;
    float* outb = out + (size_t)b * (size_t)(NC * NK);

    for (int c = w; c < NC; c += NT / 64) {
        const float* row = xb + (size_t)c * NN;
        float a[NK];
#pragma unroll
        for (int k = 0; k < NK; ++k) a[k] = 0.f;

        {
            float4 v = *(const float4*)(row + 4 * lane);
            unsigned am = assign_u[lane];
            float vv[4] = {v.x, v.y, v.z, v.w};
#pragma unroll
            for (int r = 0; r < 4; ++r) {
                int ar = (int)((am >> (8 * r)) & 0xffu);
#pragma unroll
                for (int k = 0; k < NK; ++k) a[k] += (ar == k) ? vv[r] : 0.f;
            }
        }
        if (lane < 8) {   // n = 256..287 remainder
            float4 v = *(const float4*)(row + 256 + 4 * lane);
            unsigned am = assign_u[64 + lane];
            float vv[4] = {v.x, v.y, v.z, v.w};
#pragma unroll
            for (int r = 0; r < 4; ++r) {
                int ar = (int)((am >> (8 * r)) & 0xffu);
#pragma unroll
                for (int k = 0; k < NK; ++k) a[k] += (ar == k) ? vv[r] : 0.f;
            }
        }

        // 64-lane butterfly: every lane ends with the full sums
#pragma unroll
        for (int off = 1; off < 64; off <<= 1) {
#pragma unroll
            for (int k = 0; k < NK; ++k) a[k] += __shfl_xor(a[k], off, 64);
        }

        if (lane < NK) {
            float val = a[0];
            if (lane == 1) val = a[1];
            else if (lane == 2) val = a[2];
            else if (lane == 3) val = a[3];
            else if (lane == 4) val = a[4];
            else if (lane == 5) val = a[5];
            outb[(size_t)c * NK + lane] = val * inv_s[lane];
        }
    }
}

extern "C" void kernel_launch(void* const* d_in, const int* in_sizes, int n_in,
                              void* d_out, int out_size, void* d_ws, size_t ws_size,
                              hipStream_t stream) {
    const float* x = (const float*)d_in[0];
    const float* clusters = (const float*)d_in[1];
    float* out = (float*)d_out;
    hipLaunchKernelGGL(cluster_kernel, dim3(NB), dim3(NT), 0, stream,
                       x, clusters, out);
}

// Round 2
// 892.685 us; speedup vs baseline: 1.1568x; 1.1568x over previous
//
#include <hip/hip_runtime.h>

// Problem: B=256, C=2048, N=H*W=288, K=6, fp32.
// out[b,c,k] = mean over {n: argmin_k dist(x[b,:,n], cluster_k)} of x[b,c,n], 0 if empty.
// Memory-bound: x streamed twice, but phase-2 re-read hits L3 (FETCH ~1x of x).
// R2: phase-2 uses 16-lane groups (4 c/wave) -> 6 shuffles per c instead of 36;
//     cnorm hoisted out of the phase-1 inner loop (waves 0-5 compute it once).

#define NB 256
#define NC 2048
#define NN 288
#define NK 6
#define NT 1024
#define NJ 72   // n-groups of 4 (72*4 = 288)
#define NP 14   // c-parallel slices; 72*14 = 1008 active threads in phase 1

__global__ __launch_bounds__(NT) void cluster_kernel(
    const float* __restrict__ x,
    const float* __restrict__ cl,
    float* __restrict__ out)
{
    // fp64 partial dots folded 14 -> 4 slices: 4*288*6*8 = 55,296 B
    __shared__ double part[4][NN][NK];
    __shared__ double cnorm_s[NK];
    __shared__ unsigned assign_u[NN / 4];   // assignment bytes, 4 n per word
    __shared__ int counts[NK];
    __shared__ float inv_s[NK];

    const int tid = threadIdx.x;
    const int b = blockIdx.x;
    const float* xb = x + (size_t)b * (size_t)(NC * NN);

    if (tid < NK) counts[tid] = 0;

    const int j = tid % NJ;     // n-group: n = 4j..4j+3
    const int p = tid / NJ;     // c-slice: c = p, p+14, ...
    const int w = tid >> 6;
    const int lane = tid & 63;

    // ---- cnorm: waves 0..5 each own one k (runs before their main-loop work) ----
    if (w < NK) {
        const int k = w;
        double s = 0.0;
#pragma unroll 4
        for (int c = lane; c < NC; c += 64) {
            double d = (double)cl[k * NC + c];
            s += d * d;
        }
#pragma unroll
        for (int off = 1; off < 64; off <<= 1) s += __shfl_xor(s, off, 64);
        if (lane == 0) cnorm_s[k] = s;
    }

    // ---------------- Phase 1: dot[n][k] = sum_c x[b,c,n] * cl[k][c] ----------------
    double acc[4][NK];
#pragma unroll
    for (int r = 0; r < 4; ++r)
#pragma unroll
        for (int k = 0; k < NK; ++k) acc[r][k] = 0.0;

    if (p < NP) {
#pragma unroll 2
        for (int c = p; c < NC; c += NP) {
            float4 v = *(const float4*)(xb + (size_t)c * NN + 4 * j);
            double vx = v.x, vy = v.y, vz = v.z, vw = v.w;
#pragma unroll
            for (int k = 0; k < NK; ++k) {
                double ck = (double)cl[k * NC + c];
                acc[0][k] += vx * ck;
                acc[1][k] += vy * ck;
                acc[2][k] += vz * ck;
                acc[3][k] += vw * ck;
            }
        }
    }

    // fold 14 c-slices into 4 LDS partials: part[q] accumulates p in {q, q+4, q+8, q+12}
    if (p < 4) {
#pragma unroll
        for (int r = 0; r < 4; ++r)
#pragma unroll
            for (int k = 0; k < NK; ++k) part[p][4 * j + r][k] = acc[r][k];
    }
    __syncthreads();
    if (p >= 4 && p < 8) {
#pragma unroll
        for (int r = 0; r < 4; ++r)
#pragma unroll
            for (int k = 0; k < NK; ++k) part[p - 4][4 * j + r][k] += acc[r][k];
    }
    __syncthreads();
    if (p >= 8 && p < 12) {
#pragma unroll
        for (int r = 0; r < 4; ++r)
#pragma unroll
            for (int k = 0; k < NK; ++k) part[p - 8][4 * j + r][k] += acc[r][k];
    }
    __syncthreads();
    if (p >= 12 && p < NP) {
#pragma unroll
        for (int r = 0; r < 4; ++r)
#pragma unroll
            for (int k = 0; k < NK; ++k) part[p - 12][4 * j + r][k] += acc[r][k];
    }
    __syncthreads();

    // argmin_k (||c_k||^2 - 2 dot) — x_norm is common across k, drop it.
    // Strict < with ascending k == numpy first-min tie-breaking.
    if (tid < NN) {
        double best = 1e300;
        int bi = 0;
#pragma unroll
        for (int k = 0; k < NK; ++k) {
            double d = 0.0;
#pragma unroll
            for (int q = 0; q < 4; ++q) d += part[q][tid][k];
            double sc = cnorm_s[k] - 2.0 * d;
            if (sc < best) { best = sc; bi = k; }
        }
        ((unsigned char*)assign_u)[tid] = (unsigned char)bi;
        atomicAdd(&counts[bi], 1);
    }
    __syncthreads();
    if (tid < NK) inv_s[tid] = counts[tid] > 0 ? 1.0f / (float)counts[tid] : 0.0f;
    __syncthreads();

    // -------- Phase 2: 16 lanes per c, 4 c per wave-iter; 6 shuffles per c --------
    const int sub = lane >> 4;    // which of 4 c this lane serves
    const int sl = lane & 15;     // sub-lane within the 16-lane group
    float* outb = out + (size_t)b * (size_t)(NC * NK);

    for (int cb = 4 * w; cb < NC; cb += 4 * (NT / 64)) {
        const int c = cb + sub;
        const float* row = xb + (size_t)c * NN;
        float a[NK];
#pragma unroll
        for (int k = 0; k < NK; ++k) a[k] = 0.f;

#pragma unroll
        for (int t = 0; t < 4; ++t) {
            const int g = sl + 16 * t;                 // float4-group index, n = 4g..4g+3
            float4 v = *(const float4*)(row + 4 * g);
            unsigned am = assign_u[g];
            float vv[4] = {v.x, v.y, v.z, v.w};
#pragma unroll
            for (int r = 0; r < 4; ++r) {
                int ar = (int)((am >> (8 * r)) & 0xffu);
#pragma unroll
                for (int k = 0; k < NK; ++k) a[k] += (ar == k) ? vv[r] : 0.f;
            }
        }
        if (sl < 8) {   // remainder groups 64..71 (n = 256..287)
            const int g = 64 + sl;
            float4 v = *(const float4*)(row + 4 * g);
            unsigned am = assign_u[g];
            float vv[4] = {v.x, v.y, v.z, v.w};
#pragma unroll
            for (int r = 0; r < 4; ++r) {
                int ar = (int)((am >> (8 * r)) & 0xffu);
#pragma unroll
                for (int k = 0; k < NK; ++k) a[k] += (ar == k) ? vv[r] : 0.f;
            }
        }

        // butterfly within each 16-lane group: all 16 lanes end with the group's sums
#pragma unroll
        for (int off = 1; off < 16; off <<= 1) {
#pragma unroll
            for (int k = 0; k < NK; ++k) a[k] += __shfl_xor(a[k], off, 64);
        }

        if (sl < NK) {
            float val = a[0];
            if (sl == 1) val = a[1];
            else if (sl == 2) val = a[2];
            else if (sl == 3) val = a[3];
            else if (sl == 4) val = a[4];
            else if (sl == 5) val = a[5];
            outb[(size_t)c * NK + sl] = val * inv_s[sl];
        }
    }
}

extern "C" void kernel_launch(void* const* d_in, const int* in_sizes, int n_in,
                              void* d_out, int out_size, void* d_ws, size_t ws_size,
                              hipStream_t stream) {
    const float* x = (const float*)d_in[0];
    const float* clusters = (const float*)d_in[1];
    float* out = (float*)d_out;
    hipLaunchKernelGGL(cluster_kernel, dim3(NB), dim3(NT), 0, stream,
                       x, clusters, out);
}